// Round 15
// baseline (368.018 us; speedup 1.0000x reference)
//
#include <hip/hip_runtime.h>
#include <math.h>

#define BATCH 64
#define NPG 1024
#define NT (BATCH*NPG)        // 65536 nodes
#define EPER 32768
#define ETOT (BATCH*EPER)     // 2097152 edges

typedef __attribute__((ext_vector_type(4))) float f32x4;
typedef __attribute__((ext_vector_type(8))) short s16x8;

__device__ __forceinline__ float lky(float x){ return x > 0.f ? x : 0.01f*x; }
__device__ __forceinline__ unsigned short f2bf(float f){
    unsigned u = __float_as_uint(f);
    u = u + 0x7FFFu + ((u >> 16) & 1u);      // RNE
    return (unsigned short)(u >> 16);
}
__device__ __forceinline__ float bf2f_lo(unsigned v){ return __uint_as_float(v << 16); }
__device__ __forceinline__ float bf2f_hi(unsigned v){ return __uint_as_float(v & 0xFFFF0000u); }

// ---------------- fp32 -> bf16 cast (vectorized, coalesced) ----------------
__global__ void k_castx(const float* __restrict__ in, unsigned short* __restrict__ out, int n4){
    int i = blockIdx.x*256 + threadIdx.x;
    if (i < n4){
        float4 v = ((const float4*)in)[i];
        ushort4 o = { f2bf(v.x), f2bf(v.y), f2bf(v.z), f2bf(v.w) };
        ((ushort4*)out)[i] = o;
    }
}

// ---------------- weight prep: f32 [k][n] -> bf16 [n][k] (transposed) ----------------
__global__ void k_wprep(const float* __restrict__ W1l, const float* __restrict__ W1r,
                        const float* __restrict__ W2l, const float* __restrict__ W2r,
                        unsigned short* __restrict__ wt){
    int i = blockIdx.x*256 + threadIdx.x;   // 0..49151
    if (i < 16384){ int k = i >> 7, n = i & 127; wt[n*128 + k] = f2bf(W1l[i]); }
    else if (i < 32768){ int j = i - 16384; int k = j >> 7, n = j & 127; wt[16384 + n*128 + k] = f2bf(W1r[j]); }
    else if (i < 40960){ int j = i - 32768; int k = j >> 6, n = j & 63; wt[32768 + n*128 + k] = f2bf(W2l[j]); }
    else if (i < 49152){ int j = i - 40960; int k = j >> 6, n = j & 63; wt[40960 + n*128 + k] = f2bf(W2r[j]); }
}

// ---------------- sum(a^2) via per-graph LDS nibble histogram ----------------
__global__ void __launch_bounds__(1024) k_a2lds(const int* __restrict__ src, const int* __restrict__ dst,
                                                unsigned* __restrict__ acc_out){
    __shared__ unsigned nib[32768];   // 128 KB = 262144 nibble counters
    __shared__ unsigned red[16];
    int b = blockIdx.x, pass = blockIdx.y, tid = threadIdx.x;
    for (int i = tid; i < 32768; i += 1024) nib[i] = 0;
    __syncthreads();
    int base = b*EPER;
    for (int i = tid; i < EPER; i += 1024){
        unsigned key = (((unsigned)src[base+i] & 1023u) << 10) | ((unsigned)dst[base+i] & 1023u);
        if ((int)(key >> 18) == pass)
            atomicAdd(&nib[(key & 0x3FFFFu) >> 3], 1u << ((key & 7u)*4u));
    }
    __syncthreads();
    unsigned local = 0;
    for (int i = tid; i < 32768; i += 1024){
        unsigned w = nib[i];
        if (w){
            #pragma unroll
            for (int q = 0; q < 8; q++){ unsigned c = (w >> (4*q)) & 15u; local += c*c; }
        }
    }
    for (int o = 32; o; o >>= 1) local += __shfl_xor(local, o);
    if ((tid & 63) == 0) red[tid >> 6] = local;
    __syncthreads();
    if (tid == 0){
        unsigned s = 0;
        for (int q = 0; q < 16; q++) s += red[q];
        atomicAdd(acc_out, s);
    }
}

// ---------------- atomic-free CSR build: one block per (graph, direction) ----------------
__global__ void __launch_bounds__(1024) k_csr(const int* __restrict__ src, const int* __restrict__ dst,
                                              int* __restrict__ ipd, int* __restrict__ ips,
                                              unsigned short* __restrict__ lst_d,
                                              unsigned short* __restrict__ lst_s){
    __shared__ unsigned eds[EPER];    // 128 KB packed (s<<10)|d
    __shared__ int cnt[1024];
    __shared__ int buf[1024];
    int g = blockIdx.x, which = blockIdx.y, tid = threadIdx.x;
    cnt[tid] = 0;
    __syncthreads();
    int base = g*EPER;
    for (int i = tid; i < EPER; i += 1024){
        unsigned s = (unsigned)src[base+i] & 1023u;
        unsigned d = (unsigned)dst[base+i] & 1023u;
        eds[i] = (s << 10) | d;
        atomicAdd(&cnt[which ? s : d], 1);          // LDS atomic
    }
    __syncthreads();
    int v = cnt[tid];
    int x = v;
    buf[tid] = x; __syncthreads();
    for (int off = 1; off < 1024; off <<= 1){
        int t = (tid >= off) ? buf[tid - off] : 0;
        __syncthreads();
        x += t; buf[tid] = x; __syncthreads();
    }
    int excl = x - v;
    int* ip = which ? ips : ipd;
    ip[g*1024 + tid] = base + excl;
    if (g == 0 && tid == 0) ip[NT] = ETOT;
    cnt[tid] = excl;                                 // cursor
    __syncthreads();
    unsigned short* lst = which ? lst_s : lst_d;
    for (int i = tid; i < EPER; i += 1024){
        unsigned key = eds[i];
        unsigned d = key & 1023u, s = key >> 10;
        unsigned idx = which ? s : d;
        unsigned val = which ? d : s;
        int p = atomicAdd(&cnt[idx], 1);             // LDS atomic
        lst[base + p] = (unsigned short)val;
    }
}

// ---------------- LDS-staged bf16 gather v3: 32-feature table (72 KB -> 2 blocks/CU) ----------------
template<int MODE, int TD>
__global__ void __launch_bounds__(1024) k_aggl(
        const unsigned short* __restrict__ X, const int* __restrict__ indptr,
        const unsigned short* __restrict__ lst,
        const unsigned short* __restrict__ R, const float* __restrict__ bias,
        unsigned short* __restrict__ out){
    __shared__ uint2 tab[1024*9];     // 73,728 B: 1024 rows x (32 bf16 + 8 B pad)
    constexpr int PPG = (TD == 128) ? 8 : 4;     // parts per graph
    int bid = blockIdx.x;
    int xcd = bid & 7, j = bid >> 3;
    int gi = j / PPG, part = j - gi*PPG;
    int graph = xcd + 8*gi;
    int fpart = part >> 1;
    int npart = part & 1;
    int foff = fpart*32;
    int nbase_loc = npart*512;
    int tid = threadIdx.x;
    int gb = graph*NPG;
    for (int i = tid; i < 8192; i += 1024){
        int row = i >> 3, q = i & 7;
        tab[row*9 + q] = *(const uint2*)&X[(size_t)(gb+row)*TD + foff + q*4];
    }
    __syncthreads();
    int g = tid & 7;
    for (int c = 0; c < 4; c++){
        int node = gb + nbase_loc + c*128 + (tid >> 3);
        int st = indptr[node], en = indptr[node+1];
        float a0 = 0.f, a1 = 0.f, a2 = 0.f, a3 = 0.f;
        int e = st;
        for (; e + 4 <= en; e += 4){
            int r0 = lst[e+0], r1 = lst[e+1], r2 = lst[e+2], r3 = lst[e+3];
            uint2 v0 = tab[r0*9 + g];
            uint2 v1 = tab[r1*9 + g];
            uint2 v2 = tab[r2*9 + g];
            uint2 v3 = tab[r3*9 + g];
            a0 += bf2f_lo(v0.x) + bf2f_lo(v1.x) + bf2f_lo(v2.x) + bf2f_lo(v3.x);
            a1 += bf2f_hi(v0.x) + bf2f_hi(v1.x) + bf2f_hi(v2.x) + bf2f_hi(v3.x);
            a2 += bf2f_lo(v0.y) + bf2f_lo(v1.y) + bf2f_lo(v2.y) + bf2f_lo(v3.y);
            a3 += bf2f_hi(v0.y) + bf2f_hi(v1.y) + bf2f_hi(v2.y) + bf2f_hi(v3.y);
        }
        for (; e < en; e++){
            uint2 v = tab[lst[e]*9 + g];
            a0 += bf2f_lo(v.x); a1 += bf2f_hi(v.x);
            a2 += bf2f_lo(v.y); a3 += bf2f_hi(v.y);
        }
        if (MODE >= 1){
            int dg = en - st;
            float inv = 1.f/(float)(dg > 1 ? dg : 1);
            a0 *= inv; a1 *= inv; a2 *= inv; a3 *= inv;
        }
        if (MODE == 2){
            uint2 r = *(const uint2*)&R[(size_t)node*TD + foff + 4*g];
            a0 = lky(a0 + bf2f_lo(r.x) + bias[foff + 4*g + 0]);
            a1 = lky(a1 + bf2f_hi(r.x) + bias[foff + 4*g + 1]);
            a2 = lky(a2 + bf2f_lo(r.y) + bias[foff + 4*g + 2]);
            a3 = lky(a3 + bf2f_hi(r.y) + bias[foff + 4*g + 3]);
        }
        uint2 pk;
        pk.x = (unsigned)f2bf(a0) | ((unsigned)f2bf(a1) << 16);
        pk.y = (unsigned)f2bf(a2) | ((unsigned)f2bf(a3) << 16);
        *(uint2*)&out[(size_t)node*TD + foff + 4*g] = pk;
    }
}

// ---------------- MFMA dual-B GEMM v3: bf16 A, pre-transposed bf16 weights ----------------
template<int N>
__global__ void __launch_bounds__(512) k_mfma2b(
        const unsigned short* __restrict__ Ah, const unsigned short* __restrict__ Wt1,
        const unsigned short* __restrict__ Wt2, unsigned short* __restrict__ C1,
        unsigned short* __restrict__ C2){
    __shared__ unsigned short ldsB[2*N*128];
    int tid = threadIdx.x;
    for (int i = tid; i < N*64; i += 512){
        int n = i >> 6, kk = i & 63;
        int swz = (n*256 + 4*kk) ^ ((n & 7) << 4);
        *(unsigned*)((char*)ldsB + swz)         = ((const unsigned*)Wt1)[i];
        *(unsigned*)((char*)ldsB + N*256 + swz) = ((const unsigned*)Wt2)[i];
    }
    __syncthreads();
    int wave = tid >> 6, l = tid & 63;
    int lr = l & 15, lg = l >> 4;
    constexpr int NF = N/16;
    int arow = blockIdx.x*128 + wave*16 + lr;
    f32x4 acc1[NF], acc2[NF];
    f32x4 zv = {0.f, 0.f, 0.f, 0.f};
    #pragma unroll
    for (int nf = 0; nf < NF; nf++){ acc1[nf] = zv; acc2[nf] = zv; }
    #pragma unroll
    for (int ks = 0; ks < 4; ks++){
        s16x8 af = *(const s16x8*)(Ah + (size_t)arow*128 + ks*32 + lg*8);
        #pragma unroll
        for (int nf = 0; nf < NF; nf++){
            int n = nf*16 + lr;
            int swz = (n*256 + ks*64 + lg*16) ^ ((n & 7) << 4);
            s16x8 b1 = *(const s16x8*)((const char*)ldsB + swz);
            s16x8 b2 = *(const s16x8*)((const char*)ldsB + N*256 + swz);
            acc1[nf] = __builtin_amdgcn_mfma_f32_16x16x32_bf16(af, b1, acc1[nf], 0, 0, 0);
            acc2[nf] = __builtin_amdgcn_mfma_f32_16x16x32_bf16(af, b2, acc2[nf], 0, 0, 0);
        }
    }
    int orow = blockIdx.x*128 + wave*16 + lg*4;
    #pragma unroll
    for (int nf = 0; nf < NF; nf++){
        int c = nf*16 + lr;
        #pragma unroll
        for (int j = 0; j < 4; j++){
            size_t idx = (size_t)(orow + j)*N + c;
            C1[idx] = f2bf(acc1[nf][j]);
            C2[idx] = f2bf(acc2[nf][j]);
        }
    }
}

// ---------------- fp32 dual GEMM (head only): C = act(A1@W1 [+ A2@W2] + bias) ----------------
__global__ void __launch_bounds__(256) k_gemm(
        const float* __restrict__ A1, const float* __restrict__ A2,
        const float* __restrict__ W1, const float* __restrict__ W2,
        const float* __restrict__ bias, void* __restrict__ C,
        int M, int Nn, int Kd, int dual, int act, int obf){
    __shared__ float sA1[16*68], sB1[16*68], sA2[16*68], sB2[16*68];
    int tid = threadIdx.x;
    int m0 = blockIdx.x*64, n0 = blockIdx.y*64;
    int tx = tid & 15, ty = tid >> 4;
    int lr = tid >> 2, lk = (tid & 3)*4;
    int wk = tid >> 4, wn = (tid & 15)*4;
    float acc[4][4] = {};
    for (int k0 = 0; k0 < Kd; k0 += 16){
        float4 a1 = *(const float4*)&A1[(size_t)(m0+lr)*Kd + k0 + lk];
        float4 w1 = *(const float4*)&W1[(size_t)(k0+wk)*Nn + n0 + wn];
        sA1[(lk+0)*68+lr] = a1.x; sA1[(lk+1)*68+lr] = a1.y;
        sA1[(lk+2)*68+lr] = a1.z; sA1[(lk+3)*68+lr] = a1.w;
        *(float4*)&sB1[wk*68+wn] = w1;
        if (dual){
            float4 a2 = *(const float4*)&A2[(size_t)(m0+lr)*Kd + k0 + lk];
            float4 w2 = *(const float4*)&W2[(size_t)(k0+wk)*Nn + n0 + wn];
            sA2[(lk+0)*68+lr] = a2.x; sA2[(lk+1)*68+lr] = a2.y;
            sA2[(lk+2)*68+lr] = a2.z; sA2[(lk+3)*68+lr] = a2.w;
            *(float4*)&sB2[wk*68+wn] = w2;
        }
        __syncthreads();
        #pragma unroll
        for (int kk = 0; kk < 16; kk++){
            float4 av = *(const float4*)&sA1[kk*68 + ty*4];
            float4 bv = *(const float4*)&sB1[kk*68 + tx*4];
            float a[4] = {av.x, av.y, av.z, av.w};
            float b[4] = {bv.x, bv.y, bv.z, bv.w};
            #pragma unroll
            for (int i = 0; i < 4; i++)
                #pragma unroll
                for (int j = 0; j < 4; j++) acc[i][j] += a[i]*b[j];
            if (dual){
                float4 av2 = *(const float4*)&sA2[kk*68 + ty*4];
                float4 bv2 = *(const float4*)&sB2[kk*68 + tx*4];
                float a2[4] = {av2.x, av2.y, av2.z, av2.w};
                float b2[4] = {bv2.x, bv2.y, bv2.z, bv2.w};
                #pragma unroll
                for (int i = 0; i < 4; i++)
                    #pragma unroll
                    for (int j = 0; j < 4; j++) acc[i][j] += a2[i]*b2[j];
            }
        }
        __syncthreads();
    }
    float bb[4] = {0.f, 0.f, 0.f, 0.f};
    if (bias){
        #pragma unroll
        for (int j = 0; j < 4; j++) bb[j] = bias[n0 + tx*4 + j];
    }
    #pragma unroll
    for (int i = 0; i < 4; i++){
        float v0 = acc[i][0]+bb[0], v1 = acc[i][1]+bb[1], v2 = acc[i][2]+bb[2], v3 = acc[i][3]+bb[3];
        if (act){ v0 = lky(v0); v1 = lky(v1); v2 = lky(v2); v3 = lky(v3); }
        size_t idx = (size_t)(m0 + ty*4 + i)*Nn + n0 + tx*4;
        if (obf){
            ushort4 o = { f2bf(v0), f2bf(v1), f2bf(v2), f2bf(v3) };
            *(ushort4*)&((unsigned short*)C)[idx] = o;
        } else {
            float4 o = { v0, v1, v2, v3 };
            *(float4*)&((float*)C)[idx] = o;
        }
    }
}

// ---------------- fused: spre = lky(agg2h + r2h + b2l); s = softmax(spre@Wm + bm); ent; bf16 out ----------------
__global__ void __launch_bounds__(256) k_gemm_wm(
        const unsigned short* __restrict__ agg2h, const unsigned short* __restrict__ r2h,
        const float* __restrict__ b2l, const float* __restrict__ Wm,
        const float* __restrict__ bm,
        unsigned short* __restrict__ Sh, float* __restrict__ ent_acc){
    __shared__ float sA[16*68], sB[16*68];
    __shared__ float red[256];
    int tid = threadIdx.x;
    int m0 = blockIdx.x*64;
    int tx = tid & 15, ty = tid >> 4;
    int lr = tid >> 2, lk = (tid & 3)*4;
    int wk = tid >> 4, wn = (tid & 15)*4;
    float acc[4][4] = {};
    for (int k0 = 0; k0 < 64; k0 += 16){
        uint2 a = *(const uint2*)&agg2h[(size_t)(m0+lr)*64 + k0 + lk];
        uint2 r = *(const uint2*)&r2h[(size_t)(m0+lr)*64 + k0 + lk];
        sA[(lk+0)*68+lr] = lky(bf2f_lo(a.x) + bf2f_lo(r.x) + b2l[k0+lk+0]);
        sA[(lk+1)*68+lr] = lky(bf2f_hi(a.x) + bf2f_hi(r.x) + b2l[k0+lk+1]);
        sA[(lk+2)*68+lr] = lky(bf2f_lo(a.y) + bf2f_lo(r.y) + b2l[k0+lk+2]);
        sA[(lk+3)*68+lr] = lky(bf2f_hi(a.y) + bf2f_hi(r.y) + b2l[k0+lk+3]);
        *(float4*)&sB[wk*68+wn] = *(const float4*)&Wm[(size_t)(k0+wk)*64 + wn];
        __syncthreads();
        #pragma unroll
        for (int kk = 0; kk < 16; kk++){
            float4 av = *(const float4*)&sA[kk*68 + ty*4];
            float4 bv = *(const float4*)&sB[kk*68 + tx*4];
            float a4[4] = {av.x, av.y, av.z, av.w};
            float b4[4] = {bv.x, bv.y, bv.z, bv.w};
            #pragma unroll
            for (int i = 0; i < 4; i++)
                #pragma unroll
                for (int j = 0; j < 4; j++) acc[i][j] += a4[i]*b4[j];
        }
        __syncthreads();
    }
    float bb[4];
    #pragma unroll
    for (int j = 0; j < 4; j++) bb[j] = bm[tx*4 + j];
    float ent_local = 0.f;
    #pragma unroll
    for (int i = 0; i < 4; i++){
        float v[4];
        #pragma unroll
        for (int j = 0; j < 4; j++) v[j] = acc[i][j] + bb[j];
        float m = fmaxf(fmaxf(v[0], v[1]), fmaxf(v[2], v[3]));
        for (int o = 1; o < 16; o <<= 1) m = fmaxf(m, __shfl_xor(m, o));
        float e[4];
        float sm = 0.f;
        #pragma unroll
        for (int j = 0; j < 4; j++){ e[j] = __expf(v[j] - m); sm += e[j]; }
        for (int o = 1; o < 16; o <<= 1) sm += __shfl_xor(sm, o);
        float inv = 1.f/sm;
        float p[4];
        float w = 0.f;
        #pragma unroll
        for (int j = 0; j < 4; j++){
            p[j] = e[j]*inv;
            w += -p[j]*__logf(p[j] + 1e-15f);
        }
        for (int o = 1; o < 16; o <<= 1) w += __shfl_xor(w, o);
        if (tx == 0) ent_local += w;
        size_t idx = (size_t)(m0 + ty*4 + i)*64 + tx*4;
        ushort4 oh = { f2bf(p[0]), f2bf(p[1]), f2bf(p[2]), f2bf(p[3]) };
        *(ushort4*)&Sh[idx] = oh;
    }
    red[tid] = ent_local; __syncthreads();
    for (int o = 128; o; o >>= 1){ if (tid < o) red[tid] += red[tid+o]; __syncthreads(); }
    if (tid == 0) atomicAdd(ent_acc, red[0]);
}

// ---------------- split-K fused MFMA: partial [pooled|adjp|gram] = s^T @ [z|t|s] ----------------
// grid 256: (graph, kp). Each block reduces 256 of 1024 rows -> pbuf[graph][kp][64][256].
__global__ void __launch_bounds__(1024) k_spmm(
        const unsigned short* __restrict__ Sh, const unsigned short* __restrict__ Zh,
        const unsigned short* __restrict__ Th, float* __restrict__ pbuf){
    __shared__ unsigned short At[64*72];    // A^T: [m 64][k 64]
    __shared__ unsigned short Bt[256*72];   // B^T: [col 256][k 64]
    int bid = blockIdx.x;
    int xcd = bid & 7, j = bid >> 3;
    int graph = xcd + 8*(j & 7);
    int kp = j >> 3;                        // 0..3
    int tid = threadIdx.x;
    int w = tid >> 6, l = tid & 63;
    int lr = l & 15, lg = l >> 4;
    int mt = w & 3, ng = w >> 2;
    f32x4 acc[4];
    f32x4 zv = {0.f, 0.f, 0.f, 0.f};
    #pragma unroll
    for (int q = 0; q < 4; q++) acc[q] = zv;
    int gb = graph*NPG;
    int sa_n = tid & 63, sa_c = (tid >> 6)*4;
    int sb_k = tid & 63, sb_g = tid >> 6;
    for (int n0 = kp*256; n0 < kp*256 + 256; n0 += 64){
        ushort4 sv = *(const ushort4*)&Sh[(size_t)(gb+n0+sa_n)*64 + sa_c];
        At[(sa_c+0)*72 + sa_n] = sv.x;
        At[(sa_c+1)*72 + sa_n] = sv.y;
        At[(sa_c+2)*72 + sa_n] = sv.z;
        At[(sa_c+3)*72 + sa_n] = sv.w;
        {
            int R = gb + n0 + sb_k;
            const unsigned short* srcp;
            if (sb_g < 8)       srcp = &Zh[(size_t)R*128 + sb_g*16];
            else if (sb_g < 12) srcp = &Th[(size_t)R*64 + (sb_g-8)*16];
            else                srcp = &Sh[(size_t)R*64 + (sb_g-12)*16];
            ushort4 a0 = *(const ushort4*)(srcp);
            ushort4 a1 = *(const ushort4*)(srcp+4);
            ushort4 a2 = *(const ushort4*)(srcp+8);
            ushort4 a3 = *(const ushort4*)(srcp+12);
            int cb = sb_g*16;
            Bt[(cb+ 0)*72+sb_k]=a0.x; Bt[(cb+ 1)*72+sb_k]=a0.y; Bt[(cb+ 2)*72+sb_k]=a0.z; Bt[(cb+ 3)*72+sb_k]=a0.w;
            Bt[(cb+ 4)*72+sb_k]=a1.x; Bt[(cb+ 5)*72+sb_k]=a1.y; Bt[(cb+ 6)*72+sb_k]=a1.z; Bt[(cb+ 7)*72+sb_k]=a1.w;
            Bt[(cb+ 8)*72+sb_k]=a2.x; Bt[(cb+ 9)*72+sb_k]=a2.y; Bt[(cb+10)*72+sb_k]=a2.z; Bt[(cb+11)*72+sb_k]=a2.w;
            Bt[(cb+12)*72+sb_k]=a3.x; Bt[(cb+13)*72+sb_k]=a3.y; Bt[(cb+14)*72+sb_k]=a3.z; Bt[(cb+15)*72+sb_k]=a3.w;
        }
        __syncthreads();
        #pragma unroll
        for (int ks = 0; ks < 2; ks++){
            s16x8 af = *(const s16x8*)&At[(mt*16+lr)*72 + ks*32 + lg*8];
            #pragma unroll
            for (int q = 0; q < 4; q++){
                s16x8 bf = *(const s16x8*)&Bt[((ng*4+q)*16+lr)*72 + ks*32 + lg*8];
                acc[q] = __builtin_amdgcn_mfma_f32_16x16x32_bf16(af, bf, acc[q], 0, 0, 0);
            }
        }
        __syncthreads();
    }
    float* pb = pbuf + ((size_t)graph*4 + kp)*16384;
    #pragma unroll
    for (int q = 0; q < 4; q++){
        int col = (ng*4+q)*16 + lr;
        #pragma unroll
        for (int j2 = 0; j2 < 4; j2++){
            int m = mt*16 + lg*4 + j2;
            pb[m*256 + col] = acc[q][j2];
        }
    }
}

// ---------------- reduce partials -> pooled/adjp/gram + cross/normg ----------------
__global__ void k_spmmred(const float* __restrict__ pbuf,
                          float* __restrict__ P, float* __restrict__ AP,
                          float* __restrict__ GR,
                          float* __restrict__ crossp, float* __restrict__ normgp){
    int i = blockIdx.x*256 + threadIdx.x;   // 64*16384 = 1,048,576
    int g = i >> 14;
    int r = i & 16383;
    int m = r >> 8, col = r & 255;
    const float* pb = pbuf + (size_t)g*65536 + r;
    float v = pb[0] + pb[16384] + pb[32768] + pb[49152];
    float tr = 0.f, sq = 0.f;
    if (col < 128){
        P[((size_t)g*64 + m)*128 + col] = v;
    } else if (col < 192){
        AP[((size_t)g*64 + m)*64 + (col-128)] = v;
        if (col-128 == m) tr = v;
    } else {
        GR[((size_t)g*64 + m)*64 + (col-192)] = v;
        sq = v*v;
    }
    for (int o = 32; o; o >>= 1){ tr += __shfl_xor(tr, o); sq += __shfl_xor(sq, o); }
    __shared__ float rt[4], rs[4];
    if ((threadIdx.x & 63) == 0){ rt[threadIdx.x >> 6] = tr; rs[threadIdx.x >> 6] = sq; }
    __syncthreads();
    if (threadIdx.x == 0){
        atomicAdd(crossp, rt[0]+rt[1]+rt[2]+rt[3]);
        atomicAdd(normgp, rs[0]+rs[1]+rs[2]+rs[3]);
    }
}

// ---------------- head stage A: aggout[b] = (adjp[b] @ pooled[b]) / rowsum ----------------
__global__ void __launch_bounds__(256) k_heada(
        const float* __restrict__ AP, const float* __restrict__ P,
        float* __restrict__ aggout){
    __shared__ float sapT[64*65];
    __shared__ float sp[64*33];
    __shared__ float srs[64];
    int b = blockIdx.x, c0 = blockIdx.y*32;
    int tid = threadIdx.x;
    for (int i = tid; i < 4096; i += 256){
        int k = i >> 6, l = i & 63;
        sapT[l*65 + k] = AP[(size_t)b*4096 + i];
    }
    for (int i = tid; i < 2048; i += 256){
        int l = i >> 5, j = i & 31;
        sp[l*33 + j] = P[(size_t)b*8192 + l*128 + c0 + j];
    }
    __syncthreads();
    if (tid < 64){
        float s = 0.f;
        for (int l = 0; l < 64; l++) s += sapT[l*65 + tid];
        srs[tid] = fmaxf(s, 1.f);
    }
    __syncthreads();
    int k = tid & 63, jg = (tid >> 6)*8;
    float acc[8] = {};
    for (int l = 0; l < 64; l++){
        float a = sapT[l*65 + k];
        #pragma unroll
        for (int j = 0; j < 8; j++) acc[j] += a*sp[l*33 + jg + j];
    }
    float inv = 1.f/srs[k];
    #pragma unroll
    for (int j = 0; j < 8; j++)
        aggout[(size_t)b*8192 + k*128 + c0 + jg + j] = acc[j]*inv;
}

// ---------------- head stage C: hcacc[b,:] += h[b, chunk] @ Wc1[chunk, :] ----------------
__global__ void __launch_bounds__(256) k_head2(
        const float* __restrict__ hbuf, const float* __restrict__ Wc1,
        float* __restrict__ hcacc){
    __shared__ float sh[512];
    __shared__ float sred[256];
    int b = blockIdx.x >> 4, ch = blockIdx.x & 15;
    int tid = threadIdx.x;
    for (int i = tid; i < 512; i += 256) sh[i] = hbuf[(size_t)b*8192 + ch*512 + i];
    __syncthreads();
    int j = tid & 127, half = tid >> 7;
    float acc = 0.f;
    const float* W = Wc1 + (size_t)(ch*512 + half*256)*128;
    const float* hh = sh + half*256;
    for (int r = 0; r < 256; r++) acc += hh[r]*W[(size_t)r*128 + j];
    sred[tid] = acc; __syncthreads();
    if (tid < 128) atomicAdd(&hcacc[(size_t)b*128 + tid], sred[tid] + sred[tid+128]);
}

// ---------------- head stage D: logits ----------------
__global__ void k_head3(const float* __restrict__ hcacc, const float* __restrict__ bc1,
                        const float* __restrict__ Wc2, const float* __restrict__ bc2,
                        float* __restrict__ out){
    int b = blockIdx.x, t = threadIdx.x;   // 128 threads
    float hc = lky(hcacc[(size_t)b*128 + t] + bc1[t]);
    float p = hc*Wc2[t];
    for (int o = 32; o; o >>= 1) p += __shfl_xor(p, o);
    __shared__ float r2[2];
    if ((t & 63) == 0) r2[t >> 6] = p;
    __syncthreads();
    if (t == 0) out[b] = r2[0] + r2[1] + bc2[0];
}

__global__ void k_finalize(const unsigned int* __restrict__ a2,
                           const float* __restrict__ cross,
                           const float* __restrict__ normg,
                           const float* __restrict__ ent,
                           float* __restrict__ out){
    float ss = (float)(*a2) - 2.f*(*cross) + (*normg);
    if (ss < 0.f) ss = 0.f;
    float link = sqrtf(ss) / 67108864.f;     // a.size
    out[64] = link + (*ent)/(float)NT;
}

extern "C" void kernel_launch(void* const* d_in, const int* in_sizes, int n_in,
                              void* d_out, int out_size, void* d_ws, size_t ws_size,
                              hipStream_t stream){
    const float* x    = (const float*)d_in[0];
    const int*   ei   = (const int*)d_in[1];
    const int*   src  = ei;
    const int*   dst  = ei + ETOT;
    const float* W1l  = (const float*)d_in[5];
    const float* b1l  = (const float*)d_in[6];
    const float* W1r  = (const float*)d_in[7];
    const float* W2l  = (const float*)d_in[8];
    const float* b2l  = (const float*)d_in[9];
    const float* W2r  = (const float*)d_in[10];
    const float* Wm   = (const float*)d_in[11];
    const float* bm   = (const float*)d_in[12];
    const float* Wrel = (const float*)d_in[13];
    const float* Wroot= (const float*)d_in[14];
    const float* broot= (const float*)d_in[15];
    const float* Wc1  = (const float*)d_in[16];
    const float* bc1  = (const float*)d_in[17];
    const float* Wc2  = (const float*)d_in[18];
    const float* bc2  = (const float*)d_in[19];
    float* out = (float*)d_out;

    char* w = (char*)d_ws;
    size_t off = 0;
    auto take = [&](size_t bytes)->void*{
        void* p = w + off; off = (off + bytes + 255) & ~(size_t)255; return p;
    };
    const size_t MB = 1024*1024;
    // --- small zeroed zone ---
    float* hcacc  = (float*)take((size_t)BATCH*128*4);
    float* accb   = (float*)take(64);
    size_t zero_small = off;
    // --- non-zeroed ---
    unsigned short* wt = (unsigned short*)take((size_t)49152*2);
    float* pooled = (float*)take((size_t)BATCH*64*128*4);
    float* adjp   = (float*)take((size_t)BATCH*64*64*4);
    float* gram   = (float*)take((size_t)BATCH*64*64*4);
    int*   ipd   = (int*)take((size_t)(NT+1)*4);
    int*   ips   = (int*)take((size_t)(NT+1)*4);
    unsigned short* lst_d = (unsigned short*)take((size_t)ETOT*2);
    unsigned short* lst_s = (unsigned short*)take((size_t)ETOT*2);
    char*  regA  = (char*)take(16*MB);   // agg2h (bf16, 8 MB)
    char*  regB  = (char*)take(16*MB);   // y1h (16 MB) -> th (8 MB)
    char*  regC  = (char*)take(16*MB);   // r1h (16 MB) -> [y2h 8MB | s2h 8MB]
    char*  regD  = (char*)take(16*MB);   // r2h (8 MB) -> pbuf (16 MB)
    char*  regE  = (char*)take(16*MB);   // xh (16 MB) -> zh (16 MB)
    float* hbuf  = (float*)take((size_t)BATCH*8192*4);
    float* aggo  = (float*)take((size_t)BATCH*8192*4);

    unsigned short* y1h   = (unsigned short*)regB;
    unsigned short* th    = (unsigned short*)regB;
    unsigned short* r1h   = (unsigned short*)regC;
    unsigned short* y2h   = (unsigned short*)regC;
    unsigned short* s2h   = (unsigned short*)(regC + 8*MB);
    unsigned short* r2h   = (unsigned short*)regD;
    float*          pbuf  = (float*)regD;            // overwrites r2h (dead after gemm_wm)
    unsigned short* xh    = (unsigned short*)regE;
    unsigned short* zh    = (unsigned short*)regE;   // overwrites xh (dead after layer-1 GEMM)
    unsigned short* agg2h = (unsigned short*)regA;

    float* crossp = accb + 0;
    float* normgp = accb + 1;
    float* entp   = accb + 2;
    unsigned int* a2p = (unsigned int*)(accb + 3);

    hipMemsetAsync(d_ws, 0, zero_small, stream);

    // weight transpose+cast (one-time, ~98 KB) + x -> bf16
    k_wprep<<<192, 256, 0, stream>>>(W1l, W1r, W2l, W2r, wt);
    k_castx<<<NT*128/4/256, 256, 0, stream>>>(x, xh, NT*128/4);

    // sum(a^2) via LDS nibble hist
    k_a2lds<<<dim3(BATCH, 4), 1024, 0, stream>>>(src, dst, a2p);

    // atomic-free CSR build (per-graph LDS count/scan/scatter, u16 lists)
    k_csr<<<dim3(BATCH, 2), 1024, 0, stream>>>(src, dst, ipd, ips, lst_d, lst_s);

    // SAGE layer 1 (GEMM-before-gather, MFMA): y1 = x@W1l, r1 = x@W1r (bf16)
    k_mfma2b<128><<<NT/128, 512, 0, stream>>>(xh, wt, wt + 16384, y1h, r1h);
    // LDS-staged gather (72 KB table, 2 blocks/CU) + fused fin1
    k_aggl<2,128><<<512, 1024, 0, stream>>>(y1h, ipd, lst_d, r1h, b1l, zh);

    // SAGE layer 2 (MFMA): y2 = z@W2l (bf16), r2 = z@W2r (bf16)
    k_mfma2b<64><<<NT/128, 512, 0, stream>>>(zh, wt + 32768, wt + 40960, y2h, r2h);
    k_aggl<1,64><<<256, 1024, 0, stream>>>(y2h, ipd, lst_d, nullptr, nullptr, agg2h);
    // fused: spre = lky(agg2+r2+b2l); s = softmax(spre@Wm+bm) -> s2h bf16; ent
    k_gemm_wm<<<NT/64, 256, 0, stream>>>(agg2h, r2h, b2l, Wm, bm, s2h, entp);

    // t = A @ s (bf16 out)
    k_aggl<0,64><<<256, 1024, 0, stream>>>(s2h, ips, lst_s, nullptr, nullptr, th);

    // split-K fused MFMA + reduce: pooled/adjp/gram + cross + normg
    k_spmm<<<256, 1024, 0, stream>>>(s2h, zh, th, pbuf);
    k_spmmred<<<4096, 256, 0, stream>>>(pbuf, pooled, adjp, gram, crossp, normgp);

    // head: A (agg), B (dual GEMM fp32), C (split-K), D (logits)
    k_heada<<<dim3(BATCH, 4), 256, 0, stream>>>(adjp, pooled, aggo);
    k_gemm<<<dim3(BATCH*64/64, 2), 256, 0, stream>>>(aggo, pooled, Wrel, Wroot, broot, hbuf, BATCH*64, 128, 128, 1, 1, 0);
    k_head2<<<BATCH*16, 256, 0, stream>>>(hbuf, Wc1, hcacc);
    k_head3<<<BATCH, 128, 0, stream>>>(hcacc, bc1, Wc2, bc2, out);
    k_finalize<<<1, 1, 0, stream>>>(a2p, crossp, normgp, entp, out);
}

// Round 16
// 267.338 us; speedup vs baseline: 1.3766x; 1.3766x over previous
//
#include <hip/hip_runtime.h>
#include <math.h>

#define BATCH 64
#define NPG 1024
#define NT (BATCH*NPG)        // 65536 nodes
#define EPER 32768
#define ETOT (BATCH*EPER)     // 2097152 edges

typedef __attribute__((ext_vector_type(4))) float f32x4;
typedef __attribute__((ext_vector_type(8))) short s16x8;

__device__ __forceinline__ float lky(float x){ return x > 0.f ? x : 0.01f*x; }
__device__ __forceinline__ unsigned short f2bf(float f){
    unsigned u = __float_as_uint(f);
    u = u + 0x7FFFu + ((u >> 16) & 1u);      // RNE
    return (unsigned short)(u >> 16);
}
__device__ __forceinline__ float bf2f_lo(unsigned v){ return __uint_as_float(v << 16); }
__device__ __forceinline__ float bf2f_hi(unsigned v){ return __uint_as_float(v & 0xFFFF0000u); }

// ---------------- fp32 -> bf16 cast (vectorized, coalesced) ----------------
__global__ void k_castx(const float* __restrict__ in, unsigned short* __restrict__ out, int n4){
    int i = blockIdx.x*256 + threadIdx.x;
    if (i < n4){
        float4 v = ((const float4*)in)[i];
        ushort4 o = { f2bf(v.x), f2bf(v.y), f2bf(v.z), f2bf(v.w) };
        ((ushort4*)out)[i] = o;
    }
}

// ---------------- weight prep: f32 [k][n] -> bf16 [n][k] (transposed) ----------------
__global__ void k_wprep(const float* __restrict__ W1l, const float* __restrict__ W1r,
                        const float* __restrict__ W2l, const float* __restrict__ W2r,
                        unsigned short* __restrict__ wt){
    int i = blockIdx.x*256 + threadIdx.x;   // 0..49151
    if (i < 16384){ int k = i >> 7, n = i & 127; wt[n*128 + k] = f2bf(W1l[i]); }
    else if (i < 32768){ int j = i - 16384; int k = j >> 7, n = j & 127; wt[16384 + n*128 + k] = f2bf(W1r[j]); }
    else if (i < 40960){ int j = i - 32768; int k = j >> 6, n = j & 63; wt[32768 + n*128 + k] = f2bf(W2l[j]); }
    else if (i < 49152){ int j = i - 40960; int k = j >> 6, n = j & 63; wt[40960 + n*128 + k] = f2bf(W2r[j]); }
}

// ---------------- sum(a^2) via per-graph LDS nibble histogram ----------------
__global__ void __launch_bounds__(1024) k_a2lds(const int* __restrict__ src, const int* __restrict__ dst,
                                                unsigned* __restrict__ acc_out){
    __shared__ unsigned nib[32768];   // 128 KB = 262144 nibble counters
    __shared__ unsigned red[16];
    int b = blockIdx.x, pass = blockIdx.y, tid = threadIdx.x;
    for (int i = tid; i < 32768; i += 1024) nib[i] = 0;
    __syncthreads();
    int base = b*EPER;
    for (int i = tid; i < EPER; i += 1024){
        unsigned key = (((unsigned)src[base+i] & 1023u) << 10) | ((unsigned)dst[base+i] & 1023u);
        if ((int)(key >> 18) == pass)
            atomicAdd(&nib[(key & 0x3FFFFu) >> 3], 1u << ((key & 7u)*4u));
    }
    __syncthreads();
    unsigned local = 0;
    for (int i = tid; i < 32768; i += 1024){
        unsigned w = nib[i];
        if (w){
            #pragma unroll
            for (int q = 0; q < 8; q++){ unsigned c = (w >> (4*q)) & 15u; local += c*c; }
        }
    }
    for (int o = 32; o; o >>= 1) local += __shfl_xor(local, o);
    if ((tid & 63) == 0) red[tid >> 6] = local;
    __syncthreads();
    if (tid == 0){
        unsigned s = 0;
        for (int q = 0; q < 16; q++) s += red[q];
        atomicAdd(acc_out, s);
    }
}

// ---------------- atomic-free CSR build: one block per (graph, direction) ----------------
__global__ void __launch_bounds__(1024) k_csr(const int* __restrict__ src, const int* __restrict__ dst,
                                              int* __restrict__ ipd, int* __restrict__ ips,
                                              unsigned short* __restrict__ lst_d,
                                              unsigned short* __restrict__ lst_s){
    __shared__ unsigned eds[EPER];    // 128 KB packed (s<<10)|d
    __shared__ int cnt[1024];
    __shared__ int buf[1024];
    int g = blockIdx.x, which = blockIdx.y, tid = threadIdx.x;
    cnt[tid] = 0;
    __syncthreads();
    int base = g*EPER;
    for (int i = tid; i < EPER; i += 1024){
        unsigned s = (unsigned)src[base+i] & 1023u;
        unsigned d = (unsigned)dst[base+i] & 1023u;
        eds[i] = (s << 10) | d;
        atomicAdd(&cnt[which ? s : d], 1);          // LDS atomic
    }
    __syncthreads();
    int v = cnt[tid];
    int x = v;
    buf[tid] = x; __syncthreads();
    for (int off = 1; off < 1024; off <<= 1){
        int t = (tid >= off) ? buf[tid - off] : 0;
        __syncthreads();
        x += t; buf[tid] = x; __syncthreads();
    }
    int excl = x - v;
    int* ip = which ? ips : ipd;
    ip[g*1024 + tid] = base + excl;
    if (g == 0 && tid == 0) ip[NT] = ETOT;
    cnt[tid] = excl;                                 // cursor
    __syncthreads();
    unsigned short* lst = which ? lst_s : lst_d;
    for (int i = tid; i < EPER; i += 1024){
        unsigned key = eds[i];
        unsigned d = key & 1023u, s = key >> 10;
        unsigned idx = which ? s : d;
        unsigned val = which ? d : s;
        int p = atomicAdd(&cnt[idx], 1);             // LDS atomic
        lst[base + p] = (unsigned short)val;
    }
}

// ---------------- LDS-staged bf16 gather v3: 32-feature table (72 KB -> 2 blocks/CU) ----------------
template<int MODE, int TD>
__global__ void __launch_bounds__(1024) k_aggl(
        const unsigned short* __restrict__ X, const int* __restrict__ indptr,
        const unsigned short* __restrict__ lst,
        const unsigned short* __restrict__ R, const float* __restrict__ bias,
        unsigned short* __restrict__ out){
    __shared__ uint2 tab[1024*9];     // 73,728 B: 1024 rows x (32 bf16 + 8 B pad)
    constexpr int PPG = (TD == 128) ? 8 : 4;     // parts per graph
    int bid = blockIdx.x;
    int xcd = bid & 7, j = bid >> 3;
    int gi = j / PPG, part = j - gi*PPG;
    int graph = xcd + 8*gi;
    int fpart = part >> 1;
    int npart = part & 1;
    int foff = fpart*32;
    int nbase_loc = npart*512;
    int tid = threadIdx.x;
    int gb = graph*NPG;
    for (int i = tid; i < 8192; i += 1024){
        int row = i >> 3, q = i & 7;
        tab[row*9 + q] = *(const uint2*)&X[(size_t)(gb+row)*TD + foff + q*4];
    }
    __syncthreads();
    int g = tid & 7;
    for (int c = 0; c < 4; c++){
        int node = gb + nbase_loc + c*128 + (tid >> 3);
        int st = indptr[node], en = indptr[node+1];
        float a0 = 0.f, a1 = 0.f, a2 = 0.f, a3 = 0.f;
        int e = st;
        for (; e + 4 <= en; e += 4){
            int r0 = lst[e+0], r1 = lst[e+1], r2 = lst[e+2], r3 = lst[e+3];
            uint2 v0 = tab[r0*9 + g];
            uint2 v1 = tab[r1*9 + g];
            uint2 v2 = tab[r2*9 + g];
            uint2 v3 = tab[r3*9 + g];
            a0 += bf2f_lo(v0.x) + bf2f_lo(v1.x) + bf2f_lo(v2.x) + bf2f_lo(v3.x);
            a1 += bf2f_hi(v0.x) + bf2f_hi(v1.x) + bf2f_hi(v2.x) + bf2f_hi(v3.x);
            a2 += bf2f_lo(v0.y) + bf2f_lo(v1.y) + bf2f_lo(v2.y) + bf2f_lo(v3.y);
            a3 += bf2f_hi(v0.y) + bf2f_hi(v1.y) + bf2f_hi(v2.y) + bf2f_hi(v3.y);
        }
        for (; e < en; e++){
            uint2 v = tab[lst[e]*9 + g];
            a0 += bf2f_lo(v.x); a1 += bf2f_hi(v.x);
            a2 += bf2f_lo(v.y); a3 += bf2f_hi(v.y);
        }
        if (MODE >= 1){
            int dg = en - st;
            float inv = 1.f/(float)(dg > 1 ? dg : 1);
            a0 *= inv; a1 *= inv; a2 *= inv; a3 *= inv;
        }
        if (MODE == 2){
            uint2 r = *(const uint2*)&R[(size_t)node*TD + foff + 4*g];
            a0 = lky(a0 + bf2f_lo(r.x) + bias[foff + 4*g + 0]);
            a1 = lky(a1 + bf2f_hi(r.x) + bias[foff + 4*g + 1]);
            a2 = lky(a2 + bf2f_lo(r.y) + bias[foff + 4*g + 2]);
            a3 = lky(a3 + bf2f_hi(r.y) + bias[foff + 4*g + 3]);
        }
        uint2 pk;
        pk.x = (unsigned)f2bf(a0) | ((unsigned)f2bf(a1) << 16);
        pk.y = (unsigned)f2bf(a2) | ((unsigned)f2bf(a3) << 16);
        *(uint2*)&out[(size_t)node*TD + foff + 4*g] = pk;
    }
}

// ---------------- MFMA dual-B GEMM v3: bf16 A, pre-transposed bf16 weights ----------------
template<int N>
__global__ void __launch_bounds__(512) k_mfma2b(
        const unsigned short* __restrict__ Ah, const unsigned short* __restrict__ Wt1,
        const unsigned short* __restrict__ Wt2, unsigned short* __restrict__ C1,
        unsigned short* __restrict__ C2){
    __shared__ unsigned short ldsB[2*N*128];
    int tid = threadIdx.x;
    for (int i = tid; i < N*64; i += 512){
        int n = i >> 6, kk = i & 63;
        int swz = (n*256 + 4*kk) ^ ((n & 7) << 4);
        *(unsigned*)((char*)ldsB + swz)         = ((const unsigned*)Wt1)[i];
        *(unsigned*)((char*)ldsB + N*256 + swz) = ((const unsigned*)Wt2)[i];
    }
    __syncthreads();
    int wave = tid >> 6, l = tid & 63;
    int lr = l & 15, lg = l >> 4;
    constexpr int NF = N/16;
    int arow = blockIdx.x*128 + wave*16 + lr;
    f32x4 acc1[NF], acc2[NF];
    f32x4 zv = {0.f, 0.f, 0.f, 0.f};
    #pragma unroll
    for (int nf = 0; nf < NF; nf++){ acc1[nf] = zv; acc2[nf] = zv; }
    #pragma unroll
    for (int ks = 0; ks < 4; ks++){
        s16x8 af = *(const s16x8*)(Ah + (size_t)arow*128 + ks*32 + lg*8);
        #pragma unroll
        for (int nf = 0; nf < NF; nf++){
            int n = nf*16 + lr;
            int swz = (n*256 + ks*64 + lg*16) ^ ((n & 7) << 4);
            s16x8 b1 = *(const s16x8*)((const char*)ldsB + swz);
            s16x8 b2 = *(const s16x8*)((const char*)ldsB + N*256 + swz);
            acc1[nf] = __builtin_amdgcn_mfma_f32_16x16x32_bf16(af, b1, acc1[nf], 0, 0, 0);
            acc2[nf] = __builtin_amdgcn_mfma_f32_16x16x32_bf16(af, b2, acc2[nf], 0, 0, 0);
        }
    }
    int orow = blockIdx.x*128 + wave*16 + lg*4;
    #pragma unroll
    for (int nf = 0; nf < NF; nf++){
        int c = nf*16 + lr;
        #pragma unroll
        for (int j = 0; j < 4; j++){
            size_t idx = (size_t)(orow + j)*N + c;
            C1[idx] = f2bf(acc1[nf][j]);
            C2[idx] = f2bf(acc2[nf][j]);
        }
    }
}

// ---------------- fp32 dual GEMM (head only): C = act(A1@W1 [+ A2@W2] + bias) ----------------
__global__ void __launch_bounds__(256) k_gemm(
        const float* __restrict__ A1, const float* __restrict__ A2,
        const float* __restrict__ W1, const float* __restrict__ W2,
        const float* __restrict__ bias, void* __restrict__ C,
        int M, int Nn, int Kd, int dual, int act, int obf){
    __shared__ float sA1[16*68], sB1[16*68], sA2[16*68], sB2[16*68];
    int tid = threadIdx.x;
    int m0 = blockIdx.x*64, n0 = blockIdx.y*64;
    int tx = tid & 15, ty = tid >> 4;
    int lr = tid >> 2, lk = (tid & 3)*4;
    int wk = tid >> 4, wn = (tid & 15)*4;
    float acc[4][4] = {};
    for (int k0 = 0; k0 < Kd; k0 += 16){
        float4 a1 = *(const float4*)&A1[(size_t)(m0+lr)*Kd + k0 + lk];
        float4 w1 = *(const float4*)&W1[(size_t)(k0+wk)*Nn + n0 + wn];
        sA1[(lk+0)*68+lr] = a1.x; sA1[(lk+1)*68+lr] = a1.y;
        sA1[(lk+2)*68+lr] = a1.z; sA1[(lk+3)*68+lr] = a1.w;
        *(float4*)&sB1[wk*68+wn] = w1;
        if (dual){
            float4 a2 = *(const float4*)&A2[(size_t)(m0+lr)*Kd + k0 + lk];
            float4 w2 = *(const float4*)&W2[(size_t)(k0+wk)*Nn + n0 + wn];
            sA2[(lk+0)*68+lr] = a2.x; sA2[(lk+1)*68+lr] = a2.y;
            sA2[(lk+2)*68+lr] = a2.z; sA2[(lk+3)*68+lr] = a2.w;
            *(float4*)&sB2[wk*68+wn] = w2;
        }
        __syncthreads();
        #pragma unroll
        for (int kk = 0; kk < 16; kk++){
            float4 av = *(const float4*)&sA1[kk*68 + ty*4];
            float4 bv = *(const float4*)&sB1[kk*68 + tx*4];
            float a[4] = {av.x, av.y, av.z, av.w};
            float b[4] = {bv.x, bv.y, bv.z, bv.w};
            #pragma unroll
            for (int i = 0; i < 4; i++)
                #pragma unroll
                for (int j = 0; j < 4; j++) acc[i][j] += a[i]*b[j];
            if (dual){
                float4 av2 = *(const float4*)&sA2[kk*68 + ty*4];
                float4 bv2 = *(const float4*)&sB2[kk*68 + tx*4];
                float a2[4] = {av2.x, av2.y, av2.z, av2.w};
                float b2[4] = {bv2.x, bv2.y, bv2.z, bv2.w};
                #pragma unroll
                for (int i = 0; i < 4; i++)
                    #pragma unroll
                    for (int j = 0; j < 4; j++) acc[i][j] += a2[i]*b2[j];
            }
        }
        __syncthreads();
    }
    float bb[4] = {0.f, 0.f, 0.f, 0.f};
    if (bias){
        #pragma unroll
        for (int j = 0; j < 4; j++) bb[j] = bias[n0 + tx*4 + j];
    }
    #pragma unroll
    for (int i = 0; i < 4; i++){
        float v0 = acc[i][0]+bb[0], v1 = acc[i][1]+bb[1], v2 = acc[i][2]+bb[2], v3 = acc[i][3]+bb[3];
        if (act){ v0 = lky(v0); v1 = lky(v1); v2 = lky(v2); v3 = lky(v3); }
        size_t idx = (size_t)(m0 + ty*4 + i)*Nn + n0 + tx*4;
        if (obf){
            ushort4 o = { f2bf(v0), f2bf(v1), f2bf(v2), f2bf(v3) };
            *(ushort4*)&((unsigned short*)C)[idx] = o;
        } else {
            float4 o = { v0, v1, v2, v3 };
            *(float4*)&((float*)C)[idx] = o;
        }
    }
}

// ---------------- fused: spre = lky(agg2h + r2h + b2l); s = softmax(spre@Wm + bm); ent; bf16 out ----------------
__global__ void __launch_bounds__(256) k_gemm_wm(
        const unsigned short* __restrict__ agg2h, const unsigned short* __restrict__ r2h,
        const float* __restrict__ b2l, const float* __restrict__ Wm,
        const float* __restrict__ bm,
        unsigned short* __restrict__ Sh, float* __restrict__ ent_acc){
    __shared__ float sA[16*68], sB[16*68];
    __shared__ float red[256];
    int tid = threadIdx.x;
    int m0 = blockIdx.x*64;
    int tx = tid & 15, ty = tid >> 4;
    int lr = tid >> 2, lk = (tid & 3)*4;
    int wk = tid >> 4, wn = (tid & 15)*4;
    float acc[4][4] = {};
    for (int k0 = 0; k0 < 64; k0 += 16){
        uint2 a = *(const uint2*)&agg2h[(size_t)(m0+lr)*64 + k0 + lk];
        uint2 r = *(const uint2*)&r2h[(size_t)(m0+lr)*64 + k0 + lk];
        sA[(lk+0)*68+lr] = lky(bf2f_lo(a.x) + bf2f_lo(r.x) + b2l[k0+lk+0]);
        sA[(lk+1)*68+lr] = lky(bf2f_hi(a.x) + bf2f_hi(r.x) + b2l[k0+lk+1]);
        sA[(lk+2)*68+lr] = lky(bf2f_lo(a.y) + bf2f_lo(r.y) + b2l[k0+lk+2]);
        sA[(lk+3)*68+lr] = lky(bf2f_hi(a.y) + bf2f_hi(r.y) + b2l[k0+lk+3]);
        *(float4*)&sB[wk*68+wn] = *(const float4*)&Wm[(size_t)(k0+wk)*64 + wn];
        __syncthreads();
        #pragma unroll
        for (int kk = 0; kk < 16; kk++){
            float4 av = *(const float4*)&sA[kk*68 + ty*4];
            float4 bv = *(const float4*)&sB[kk*68 + tx*4];
            float a4[4] = {av.x, av.y, av.z, av.w};
            float b4[4] = {bv.x, bv.y, bv.z, bv.w};
            #pragma unroll
            for (int i = 0; i < 4; i++)
                #pragma unroll
                for (int j = 0; j < 4; j++) acc[i][j] += a4[i]*b4[j];
        }
        __syncthreads();
    }
    float bb[4];
    #pragma unroll
    for (int j = 0; j < 4; j++) bb[j] = bm[tx*4 + j];
    float ent_local = 0.f;
    #pragma unroll
    for (int i = 0; i < 4; i++){
        float v[4];
        #pragma unroll
        for (int j = 0; j < 4; j++) v[j] = acc[i][j] + bb[j];
        float m = fmaxf(fmaxf(v[0], v[1]), fmaxf(v[2], v[3]));
        for (int o = 1; o < 16; o <<= 1) m = fmaxf(m, __shfl_xor(m, o));
        float e[4];
        float sm = 0.f;
        #pragma unroll
        for (int j = 0; j < 4; j++){ e[j] = __expf(v[j] - m); sm += e[j]; }
        for (int o = 1; o < 16; o <<= 1) sm += __shfl_xor(sm, o);
        float inv = 1.f/sm;
        float p[4];
        float w = 0.f;
        #pragma unroll
        for (int j = 0; j < 4; j++){
            p[j] = e[j]*inv;
            w += -p[j]*__logf(p[j] + 1e-15f);
        }
        for (int o = 1; o < 16; o <<= 1) w += __shfl_xor(w, o);
        if (tx == 0) ent_local += w;
        size_t idx = (size_t)(m0 + ty*4 + i)*64 + tx*4;
        ushort4 oh = { f2bf(p[0]), f2bf(p[1]), f2bf(p[2]), f2bf(p[3]) };
        *(ushort4*)&Sh[idx] = oh;
    }
    red[tid] = ent_local; __syncthreads();
    for (int o = 128; o; o >>= 1){ if (tid < o) red[tid] += red[tid+o]; __syncthreads(); }
    if (tid == 0) atomicAdd(ent_acc, red[0]);
}

// ---------------- split-K fused MFMA: partial [pooled|adjp|gram] = s^T @ [z|t|s] ----------------
// grid 256: (graph, kp). Each block reduces 256 of 1024 rows -> pbuf[graph][kp][64][256].
__global__ void __launch_bounds__(1024) k_spmm(
        const unsigned short* __restrict__ Sh, const unsigned short* __restrict__ Zh,
        const unsigned short* __restrict__ Th, float* __restrict__ pbuf){
    __shared__ unsigned short At[64*72];    // A^T: [m 64][k 64]
    __shared__ unsigned short Bt[256*72];   // B^T: [col 256][k 64]
    int bid = blockIdx.x;
    int xcd = bid & 7, j = bid >> 3;
    int graph = xcd + 8*(j & 7);
    int kp = j >> 3;                        // 0..3
    int tid = threadIdx.x;
    int w = tid >> 6, l = tid & 63;
    int lr = l & 15, lg = l >> 4;
    int mt = w & 3, ng = w >> 2;
    f32x4 acc[4];
    f32x4 zv = {0.f, 0.f, 0.f, 0.f};
    #pragma unroll
    for (int q = 0; q < 4; q++) acc[q] = zv;
    int gb = graph*NPG;
    int sa_n = tid & 63, sa_c = (tid >> 6)*4;
    int sb_k = tid & 63, sb_g = tid >> 6;
    for (int n0 = kp*256; n0 < kp*256 + 256; n0 += 64){
        ushort4 sv = *(const ushort4*)&Sh[(size_t)(gb+n0+sa_n)*64 + sa_c];
        At[(sa_c+0)*72 + sa_n] = sv.x;
        At[(sa_c+1)*72 + sa_n] = sv.y;
        At[(sa_c+2)*72 + sa_n] = sv.z;
        At[(sa_c+3)*72 + sa_n] = sv.w;
        {
            int R = gb + n0 + sb_k;
            const unsigned short* srcp;
            if (sb_g < 8)       srcp = &Zh[(size_t)R*128 + sb_g*16];
            else if (sb_g < 12) srcp = &Th[(size_t)R*64 + (sb_g-8)*16];
            else                srcp = &Sh[(size_t)R*64 + (sb_g-12)*16];
            ushort4 a0 = *(const ushort4*)(srcp);
            ushort4 a1 = *(const ushort4*)(srcp+4);
            ushort4 a2 = *(const ushort4*)(srcp+8);
            ushort4 a3 = *(const ushort4*)(srcp+12);
            int cb = sb_g*16;
            Bt[(cb+ 0)*72+sb_k]=a0.x; Bt[(cb+ 1)*72+sb_k]=a0.y; Bt[(cb+ 2)*72+sb_k]=a0.z; Bt[(cb+ 3)*72+sb_k]=a0.w;
            Bt[(cb+ 4)*72+sb_k]=a1.x; Bt[(cb+ 5)*72+sb_k]=a1.y; Bt[(cb+ 6)*72+sb_k]=a1.z; Bt[(cb+ 7)*72+sb_k]=a1.w;
            Bt[(cb+ 8)*72+sb_k]=a2.x; Bt[(cb+ 9)*72+sb_k]=a2.y; Bt[(cb+10)*72+sb_k]=a2.z; Bt[(cb+11)*72+sb_k]=a2.w;
            Bt[(cb+12)*72+sb_k]=a3.x; Bt[(cb+13)*72+sb_k]=a3.y; Bt[(cb+14)*72+sb_k]=a3.z; Bt[(cb+15)*72+sb_k]=a3.w;
        }
        __syncthreads();
        #pragma unroll
        for (int ks = 0; ks < 2; ks++){
            s16x8 af = *(const s16x8*)&At[(mt*16+lr)*72 + ks*32 + lg*8];
            #pragma unroll
            for (int q = 0; q < 4; q++){
                s16x8 bf = *(const s16x8*)&Bt[((ng*4+q)*16+lr)*72 + ks*32 + lg*8];
                acc[q] = __builtin_amdgcn_mfma_f32_16x16x32_bf16(af, bf, acc[q], 0, 0, 0);
            }
        }
        __syncthreads();
    }
    float* pb = pbuf + ((size_t)graph*4 + kp)*16384;
    #pragma unroll
    for (int q = 0; q < 4; q++){
        int col = (ng*4+q)*16 + lr;
        #pragma unroll
        for (int j2 = 0; j2 < 4; j2++){
            int m = mt*16 + lg*4 + j2;
            pb[m*256 + col] = acc[q][j2];
        }
    }
}

// ---------------- reduce partials -> pooled/adjp/gram; per-block partial tr/sq (no atomics) ----------------
__global__ void k_spmmred(const float* __restrict__ pbuf,
                          float* __restrict__ P, float* __restrict__ AP,
                          float* __restrict__ GR,
                          float* __restrict__ redt, float* __restrict__ reds){
    int i = blockIdx.x*256 + threadIdx.x;   // 64*16384 = 1,048,576
    int g = i >> 14;
    int r = i & 16383;
    int m = r >> 8, col = r & 255;
    const float* pb = pbuf + (size_t)g*65536 + r;
    float v = pb[0] + pb[16384] + pb[32768] + pb[49152];
    float tr = 0.f, sq = 0.f;
    if (col < 128){
        P[((size_t)g*64 + m)*128 + col] = v;
    } else if (col < 192){
        AP[((size_t)g*64 + m)*64 + (col-128)] = v;
        if (col-128 == m) tr = v;
    } else {
        GR[((size_t)g*64 + m)*64 + (col-192)] = v;
        sq = v*v;
    }
    for (int o = 32; o; o >>= 1){ tr += __shfl_xor(tr, o); sq += __shfl_xor(sq, o); }
    __shared__ float rt[4], rs[4];
    if ((threadIdx.x & 63) == 0){ rt[threadIdx.x >> 6] = tr; rs[threadIdx.x >> 6] = sq; }
    __syncthreads();
    if (threadIdx.x == 0){
        redt[blockIdx.x] = rt[0]+rt[1]+rt[2]+rt[3];
        reds[blockIdx.x] = rs[0]+rs[1]+rs[2]+rs[3];
    }
}

// ---------------- final reduce of 4096-entry partial arrays -> cross/normg ----------------
__global__ void __launch_bounds__(1024) k_redfin(const float* __restrict__ redt,
                                                 const float* __restrict__ reds,
                                                 float* __restrict__ crossp,
                                                 float* __restrict__ normgp){
    int tid = threadIdx.x;
    float t = redt[tid] + redt[tid+1024] + redt[tid+2048] + redt[tid+3072];
    float s = reds[tid] + reds[tid+1024] + reds[tid+2048] + reds[tid+3072];
    for (int o = 32; o; o >>= 1){ t += __shfl_xor(t, o); s += __shfl_xor(s, o); }
    __shared__ float rt[16], rs[16];
    if ((tid & 63) == 0){ rt[tid >> 6] = t; rs[tid >> 6] = s; }
    __syncthreads();
    if (tid == 0){
        float st = 0.f, ss = 0.f;
        for (int q = 0; q < 16; q++){ st += rt[q]; ss += rs[q]; }
        atomicAdd(crossp, st);
        atomicAdd(normgp, ss);
    }
}

// ---------------- head stage A: aggout[b] = (adjp[b] @ pooled[b]) / rowsum ----------------
__global__ void __launch_bounds__(256) k_heada(
        const float* __restrict__ AP, const float* __restrict__ P,
        float* __restrict__ aggout){
    __shared__ float sapT[64*65];
    __shared__ float sp[64*33];
    __shared__ float srs[64];
    int b = blockIdx.x, c0 = blockIdx.y*32;
    int tid = threadIdx.x;
    for (int i = tid; i < 4096; i += 256){
        int k = i >> 6, l = i & 63;
        sapT[l*65 + k] = AP[(size_t)b*4096 + i];
    }
    for (int i = tid; i < 2048; i += 256){
        int l = i >> 5, j = i & 31;
        sp[l*33 + j] = P[(size_t)b*8192 + l*128 + c0 + j];
    }
    __syncthreads();
    if (tid < 64){
        float s = 0.f;
        for (int l = 0; l < 64; l++) s += sapT[l*65 + tid];
        srs[tid] = fmaxf(s, 1.f);
    }
    __syncthreads();
    int k = tid & 63, jg = (tid >> 6)*8;
    float acc[8] = {};
    for (int l = 0; l < 64; l++){
        float a = sapT[l*65 + k];
        #pragma unroll
        for (int j = 0; j < 8; j++) acc[j] += a*sp[l*33 + jg + j];
    }
    float inv = 1.f/srs[k];
    #pragma unroll
    for (int j = 0; j < 8; j++)
        aggout[(size_t)b*8192 + k*128 + c0 + jg + j] = acc[j]*inv;
}

// ---------------- head stage C: hcacc[b,:] += h[b, chunk] @ Wc1[chunk, :] ----------------
__global__ void __launch_bounds__(256) k_head2(
        const float* __restrict__ hbuf, const float* __restrict__ Wc1,
        float* __restrict__ hcacc){
    __shared__ float sh[512];
    __shared__ float sred[256];
    int b = blockIdx.x >> 4, ch = blockIdx.x & 15;
    int tid = threadIdx.x;
    for (int i = tid; i < 512; i += 256) sh[i] = hbuf[(size_t)b*8192 + ch*512 + i];
    __syncthreads();
    int j = tid & 127, half = tid >> 7;
    float acc = 0.f;
    const float* W = Wc1 + (size_t)(ch*512 + half*256)*128;
    const float* hh = sh + half*256;
    for (int r = 0; r < 256; r++) acc += hh[r]*W[(size_t)r*128 + j];
    sred[tid] = acc; __syncthreads();
    if (tid < 128) atomicAdd(&hcacc[(size_t)b*128 + tid], sred[tid] + sred[tid+128]);
}

// ---------------- head stage D: logits ----------------
__global__ void k_head3(const float* __restrict__ hcacc, const float* __restrict__ bc1,
                        const float* __restrict__ Wc2, const float* __restrict__ bc2,
                        float* __restrict__ out){
    int b = blockIdx.x, t = threadIdx.x;   // 128 threads
    float hc = lky(hcacc[(size_t)b*128 + t] + bc1[t]);
    float p = hc*Wc2[t];
    for (int o = 32; o; o >>= 1) p += __shfl_xor(p, o);
    __shared__ float r2[2];
    if ((t & 63) == 0) r2[t >> 6] = p;
    __syncthreads();
    if (t == 0) out[b] = r2[0] + r2[1] + bc2[0];
}

__global__ void k_finalize(const unsigned int* __restrict__ a2,
                           const float* __restrict__ cross,
                           const float* __restrict__ normg,
                           const float* __restrict__ ent,
                           float* __restrict__ out){
    float ss = (float)(*a2) - 2.f*(*cross) + (*normg);
    if (ss < 0.f) ss = 0.f;
    float link = sqrtf(ss) / 67108864.f;     // a.size
    out[64] = link + (*ent)/(float)NT;
}

extern "C" void kernel_launch(void* const* d_in, const int* in_sizes, int n_in,
                              void* d_out, int out_size, void* d_ws, size_t ws_size,
                              hipStream_t stream){
    const float* x    = (const float*)d_in[0];
    const int*   ei   = (const int*)d_in[1];
    const int*   src  = ei;
    const int*   dst  = ei + ETOT;
    const float* W1l  = (const float*)d_in[5];
    const float* b1l  = (const float*)d_in[6];
    const float* W1r  = (const float*)d_in[7];
    const float* W2l  = (const float*)d_in[8];
    const float* b2l  = (const float*)d_in[9];
    const float* W2r  = (const float*)d_in[10];
    const float* Wm   = (const float*)d_in[11];
    const float* bm   = (const float*)d_in[12];
    const float* Wrel = (const float*)d_in[13];
    const float* Wroot= (const float*)d_in[14];
    const float* broot= (const float*)d_in[15];
    const float* Wc1  = (const float*)d_in[16];
    const float* bc1  = (const float*)d_in[17];
    const float* Wc2  = (const float*)d_in[18];
    const float* bc2  = (const float*)d_in[19];
    float* out = (float*)d_out;

    char* w = (char*)d_ws;
    size_t off = 0;
    auto take = [&](size_t bytes)->void*{
        void* p = w + off; off = (off + bytes + 255) & ~(size_t)255; return p;
    };
    const size_t MB = 1024*1024;
    // --- small zeroed zone ---
    float* hcacc  = (float*)take((size_t)BATCH*128*4);
    float* accb   = (float*)take(64);
    size_t zero_small = off;
    // --- non-zeroed ---
    unsigned short* wt = (unsigned short*)take((size_t)49152*2);
    float* pooled = (float*)take((size_t)BATCH*64*128*4);
    float* adjp   = (float*)take((size_t)BATCH*64*64*4);
    float* gram   = (float*)take((size_t)BATCH*64*64*4);
    float* redt   = (float*)take((size_t)4096*4);
    float* reds   = (float*)take((size_t)4096*4);
    int*   ipd   = (int*)take((size_t)(NT+1)*4);
    int*   ips   = (int*)take((size_t)(NT+1)*4);
    unsigned short* lst_d = (unsigned short*)take((size_t)ETOT*2);
    unsigned short* lst_s = (unsigned short*)take((size_t)ETOT*2);
    char*  regA  = (char*)take(16*MB);   // agg2h (bf16, 8 MB)
    char*  regB  = (char*)take(16*MB);   // y1h (16 MB) -> th (8 MB)
    char*  regC  = (char*)take(16*MB);   // r1h (16 MB) -> [y2h 8MB | s2h 8MB]
    char*  regD  = (char*)take(16*MB);   // r2h (8 MB) -> pbuf (16 MB)
    char*  regE  = (char*)take(16*MB);   // xh (16 MB) -> zh (16 MB)
    float* hbuf  = (float*)take((size_t)BATCH*8192*4);
    float* aggo  = (float*)take((size_t)BATCH*8192*4);

    unsigned short* y1h   = (unsigned short*)regB;
    unsigned short* th    = (unsigned short*)regB;
    unsigned short* r1h   = (unsigned short*)regC;
    unsigned short* y2h   = (unsigned short*)regC;
    unsigned short* s2h   = (unsigned short*)(regC + 8*MB);
    unsigned short* r2h   = (unsigned short*)regD;
    float*          pbuf  = (float*)regD;            // overwrites r2h (dead after gemm_wm)
    unsigned short* xh    = (unsigned short*)regE;
    unsigned short* zh    = (unsigned short*)regE;   // overwrites xh (dead after layer-1 GEMM)
    unsigned short* agg2h = (unsigned short*)regA;

    float* crossp = accb + 0;
    float* normgp = accb + 1;
    float* entp   = accb + 2;
    unsigned int* a2p = (unsigned int*)(accb + 3);

    hipMemsetAsync(d_ws, 0, zero_small, stream);

    // weight transpose+cast (one-time, ~98 KB) + x -> bf16
    k_wprep<<<192, 256, 0, stream>>>(W1l, W1r, W2l, W2r, wt);
    k_castx<<<NT*128/4/256, 256, 0, stream>>>(x, xh, NT*128/4);

    // sum(a^2) via LDS nibble hist
    k_a2lds<<<dim3(BATCH, 4), 1024, 0, stream>>>(src, dst, a2p);

    // atomic-free CSR build (per-graph LDS count/scan/scatter, u16 lists)
    k_csr<<<dim3(BATCH, 2), 1024, 0, stream>>>(src, dst, ipd, ips, lst_d, lst_s);

    // SAGE layer 1 (GEMM-before-gather, MFMA): y1 = x@W1l, r1 = x@W1r (bf16)
    k_mfma2b<128><<<NT/128, 512, 0, stream>>>(xh, wt, wt + 16384, y1h, r1h);
    // LDS-staged gather (72 KB table, 2 blocks/CU) + fused fin1
    k_aggl<2,128><<<512, 1024, 0, stream>>>(y1h, ipd, lst_d, r1h, b1l, zh);

    // SAGE layer 2 (MFMA): y2 = z@W2l (bf16), r2 = z@W2r (bf16)
    k_mfma2b<64><<<NT/128, 512, 0, stream>>>(zh, wt + 32768, wt + 40960, y2h, r2h);
    k_aggl<1,64><<<256, 1024, 0, stream>>>(y2h, ipd, lst_d, nullptr, nullptr, agg2h);
    // fused: spre = lky(agg2+r2+b2l); s = softmax(spre@Wm+bm) -> s2h bf16; ent
    k_gemm_wm<<<NT/64, 256, 0, stream>>>(agg2h, r2h, b2l, Wm, bm, s2h, entp);

    // t = A @ s (bf16 out)
    k_aggl<0,64><<<256, 1024, 0, stream>>>(s2h, ips, lst_s, nullptr, nullptr, th);

    // split-K fused MFMA + atomic-free reduce: pooled/adjp/gram + cross + normg
    k_spmm<<<256, 1024, 0, stream>>>(s2h, zh, th, pbuf);
    k_spmmred<<<4096, 256, 0, stream>>>(pbuf, pooled, adjp, gram, redt, reds);
    k_redfin<<<1, 1024, 0, stream>>>(redt, reds, crossp, normgp);

    // head: A (agg), B (dual GEMM fp32), C (split-K), D (logits)
    k_heada<<<dim3(BATCH, 4), 256, 0, stream>>>(adjp, pooled, aggo);
    k_gemm<<<dim3(BATCH*64/64, 2), 256, 0, stream>>>(aggo, pooled, Wrel, Wroot, broot, hbuf, BATCH*64, 128, 128, 1, 1, 0);
    k_head2<<<BATCH*16, 256, 0, stream>>>(hbuf, Wc1, hcacc);
    k_head3<<<BATCH, 128, 0, stream>>>(hcacc, bc1, Wc2, bc2, out);
    k_finalize<<<1, 1, 0, stream>>>(a2p, crossp, normgp, entp, out);
}